// Round 16
// baseline (922.986 us; speedup 1.0000x reference)
//
#include <hip/hip_runtime.h>
#include <hip/hip_bf16.h>
#include <cstdint>

// ReportDecoder: B=512,S=49,E=1024,H=1024,V2=16,L=64,T=48, D_IN=1105
// Round 16:
//  (1) k_step: fixed counted-vmcnt pipeline. r15's uniform vmcnt(8) over-waited
//      (B reg-loads also count in vmcnt; younger-set at wait = 18, not 8).
//      New uniform-issue depth-3 scheme: prologue B(i),A(i) i=0..2; iter kt issues
//      B(kt+3)+A(kt+3) (6 ops); wait vmcnt(18) for kt=0..13, tail 12/6/0.
//      breg ring[4], A-slot ring 4x8KB.
//  (2) k_out: async 3-buffer global_load_lds pipeline (r11-proven scheme +
//      r14 swizzle), vmcnt(12/6/0); OOB B rows source-clamped (outputs skipped).
// Everything else identical to r15.

typedef __bf16 bf16_t;
typedef bf16_t bf16x8 __attribute__((ext_vector_type(8)));
typedef bf16_t bf16x4 __attribute__((ext_vector_type(4)));
typedef float  f32x4  __attribute__((ext_vector_type(4)));

#define Bn    512
#define Sn    49
#define En    1024
#define Hn    1024
#define Ln    64
#define Tn    48
#define DINn  1105
#define NOn   1090
#define HLD   1088          // h row stride (1024 h + 64 label)
#define HSTEP 557056        // 512*1088 elements per step slab

#define BM   64
#define LDSP 72             // padded K-stride for init GEMM LDS tiles

__device__ __forceinline__ float sigm(float x){ return 1.0f / (1.0f + __expf(-x)); }

// ---------- image mean ----------
__global__ __launch_bounds__(256) void k_mean(const float* __restrict__ image,
                                              bf16_t* __restrict__ imb){
  int b  = blockIdx.x;
  int e0 = threadIdx.x * 4;
  const float* p = image + (size_t)b * (Sn * En) + e0;
  float4 acc = make_float4(0.f, 0.f, 0.f, 0.f);
  for (int s = 0; s < Sn; ++s){
    float4 v = *reinterpret_cast<const float4*>(p + (size_t)s * En);
    acc.x += v.x; acc.y += v.y; acc.z += v.z; acc.w += v.w;
  }
  const float inv = 1.0f / 49.0f;
  bf16x4 o;
  o[0] = (bf16_t)(acc.x * inv); o[1] = (bf16_t)(acc.y * inv);
  o[2] = (bf16_t)(acc.z * inv); o[3] = (bf16_t)(acc.w * inv);
  *reinterpret_cast<bf16x4*>(imb + (size_t)b * En + e0) = o;
}

// ---------- conversions: whht packed tiles, fc weights, wimg, label scatter ----------
__global__ __launch_bounds__(256) void k_convert(
    const float* __restrict__ w_hh,  const float* __restrict__ fc_h_w,
    const float* __restrict__ fc_m_w,const float* __restrict__ fc_w,
    const float* __restrict__ label, const float* __restrict__ w_ih,
    bf16_t* __restrict__ whht,  bf16_t* __restrict__ fchwb,
    bf16_t* __restrict__ fcmwb, bf16_t* __restrict__ fcwb,
    bf16_t* __restrict__ wimgb, bf16_t* __restrict__ hs){
  const int E0 = 32 * 17 * 16 * 512;     // whht packed (= 4096*1088)
  const int E1 = E0 + 1024 * 1024;
  const int E2 = E1 + 1024 * 1024;
  const int E3 = E2 + 1090 * 1024;
  const int E4 = E3 + 4096 * 1024;
  const int E5 = E4 + 48 * 512 * 64;
  int stride = gridDim.x * blockDim.x;
  for (int i = blockIdx.x * blockDim.x + threadIdx.x; i < E5; i += stride){
    if (i < E0){
      int e = i & 7, l = (i >> 3) & 63, g = (i >> 9) & 15;
      int rest = i >> 13;                // cb*17 + kt
      int kt = rest % 17, cbb = rest / 17;
      int wv = g >> 2, ni = (g >> 1) & 1, kk = g & 1;
      int n = wv * 1024 + cbb * 32 + ni * 16 + (l & 15);
      int k = kt * 64 + kk * 32 + (l >> 4) * 8 + e;
      float v = (k < 1024) ? w_hh[(size_t)n * 1024 + k]
                           : w_ih[(size_t)n * DINn + 1041 + (k - 1024)];
      whht[i] = (bf16_t)v;
    } else if (i < E1){ int j = i - E0; fchwb[j] = (bf16_t)fc_h_w[j]; }
    else if (i < E2){ int j = i - E1; fcmwb[j] = (bf16_t)fc_m_w[j]; }
    else if (i < E3){ int j = i - E2; fcwb[j]  = (bf16_t)fc_w[j]; }
    else if (i < E4){
      int j = i - E3; int n = j >> 10, k = j & 1023;
      wimgb[j] = (bf16_t)w_ih[(size_t)n * DINn + k];
    } else {
      int j = i - E4;
      int t = j >> 15, rem = j & 32767, row = rem >> 6, c = rem & 63;
      float v = (t == 0) ? 0.f : label[(size_t)row * (Sn * Ln) + (t - 1) * 64 + c];
      hs[((size_t)t * 512 + row) * HLD + 1024 + c] = (bf16_t)v;
    }
  }
}

// ---------- xconst pre-pass ----------
__global__ __launch_bounds__(256) void k_vpc(const float* __restrict__ w_ih,
                                             const float* __restrict__ vp,
                                             const float* __restrict__ b_ih,
                                             const float* __restrict__ b_hh,
                                             float* __restrict__ xconst){
  int idx = blockIdx.x * 256 + threadIdx.x;
  int b = idx >> 12, n = idx & 4095;
  float acc = b_ih[n] + b_hh[n];
  const float* w = w_ih + (size_t)n * DINn + En;
  const float* v = vp + b * 16;
  #pragma unroll
  for (int j = 0; j < 16; ++j) acc += v[j] * w[j];
  xconst[idx] = acc;
}

// ---------- padded-LDS helpers (init GEMM) ----------
__device__ __forceinline__ void stageAp(bf16_t* sA, const bf16_t* gptr, int ld, int tid){
  #pragma unroll
  for (int i = 0; i < 2; ++i){
    int idx = tid + i * 256;
    int r = idx >> 3, v = idx & 7;
    *reinterpret_cast<bf16x8*>(sA + r * LDSP + v * 8) =
      *reinterpret_cast<const bf16x8*>(gptr + (size_t)r * ld + v * 8);
  }
}

__device__ __forceinline__ void mma_tile(const bf16_t* sA, const bf16_t* sB,
                                         f32x4 (&acc)[4][2], int lane, int w){
  int lr = lane & 15;
  int lk = (lane >> 4) * 8;
  #pragma unroll
  for (int kk = 0; kk < 2; ++kk){
    bf16x8 a[4], bb[2];
    #pragma unroll
    for (int mi = 0; mi < 4; ++mi)
      a[mi] = *reinterpret_cast<const bf16x8*>(sA + (mi * 16 + lr) * LDSP + kk * 32 + lk);
    #pragma unroll
    for (int ni = 0; ni < 2; ++ni)
      bb[ni] = *reinterpret_cast<const bf16x8*>(sB + (w * 32 + ni * 16 + lr) * LDSP + kk * 32 + lk);
    #pragma unroll
    for (int mi = 0; mi < 4; ++mi)
      #pragma unroll
      for (int ni = 0; ni < 2; ++ni)
        acc[mi][ni] = __builtin_amdgcn_mfma_f32_16x16x32_bf16(a[mi], bb[ni], acc[mi][ni], 0, 0, 0);
  }
}

// ---------- init GEMM: h0 (stride 1088), m0, xconst += im@Wimg^T ----------
__global__ __launch_bounds__(256) void k_init_gemm(
    const bf16_t* __restrict__ imb,  const bf16_t* __restrict__ fchw,
    const bf16_t* __restrict__ fcmw, const bf16_t* __restrict__ wimg,
    const float* __restrict__ fc_h_b,const float* __restrict__ fc_m_b,
    bf16_t* __restrict__ h0, float* __restrict__ m0, float* __restrict__ xconst){
  __shared__ __align__(16) unsigned char smem[(BM + 128) * LDSP * 2];
  bf16_t* sA = (bf16_t*)smem;
  bf16_t* sB = (bf16_t*)(smem + BM * LDSP * 2);
  int tid = threadIdx.x;
  int cb = blockIdx.x, rb = blockIdx.y;
  int nBase = cb * 128;
  const bf16_t* Bsrc; int nOff;
  if      (nBase < 1024){ Bsrc = fchw; nOff = nBase; }
  else if (nBase < 2048){ Bsrc = fcmw; nOff = nBase - 1024; }
  else                  { Bsrc = wimg; nOff = nBase - 2048; }

  f32x4 acc[4][2] = {};
  int lane = tid & 63, w = tid >> 6;
  for (int kt = 0; kt < 16; ++kt){
    stageAp(sA, imb + (size_t)(rb * 64) * 1024 + kt * 64, 1024, tid);
    #pragma unroll
    for (int i = 0; i < 4; ++i){
      int idx = tid + i * 256;
      int r = idx >> 3, v = idx & 7;
      *reinterpret_cast<bf16x8*>(sB + r * LDSP + v * 8) =
        *reinterpret_cast<const bf16x8*>(Bsrc + (size_t)(nOff + r) * 1024 + kt * 64 + v * 8);
    }
    __syncthreads();
    mma_tile(sA, sB, acc, lane, w);
    __syncthreads();
  }
  int lr = lane & 15, lg = lane >> 4;
  #pragma unroll
  for (int mi = 0; mi < 4; ++mi)
    #pragma unroll
    for (int ni = 0; ni < 2; ++ni)
      #pragma unroll
      for (int r = 0; r < 4; ++r){
        int ng   = nBase + w * 32 + ni * 16 + lr;
        int rowg = rb * 64 + mi * 16 + lg * 4 + r;
        float v = acc[mi][ni][r];
        if (ng < 1024){
          h0[(size_t)rowg * HLD + ng] = (bf16_t)tanhf(v + fc_h_b[ng]);
        } else if (ng < 2048){
          int n = ng - 1024;
          m0[(size_t)rowg * 1024 + n] = tanhf(v + fc_m_b[n]);
        } else {
          int n = ng - 2048;
          xconst[(size_t)rowg * 4096 + n] += v;
        }
      }
}

// ---------- per-step fused gates GEMM + LSTM cell ----------
// grid (32,8). Uniform-issue depth-3 pipeline: iter kt issues B(kt+3) (4 VMEM) +
// A(kt+3) stage (2 VMEM); wait vmcnt(18) (= exact younger-set), tail 12/6/0.
__global__ __launch_bounds__(256) void k_step(
    const bf16_t* __restrict__ hin,
    bf16_t* __restrict__ hout,
    const bf16_t* __restrict__ whht,   // packed [cb][17][16][512]
    const float* __restrict__ xconst,  // 512 x 4096
    const float* __restrict__ w_ih,    // begin col 1040
    float* __restrict__ m,             // 512 x 1024 f32
    int t){
  __shared__ __align__(16) unsigned char smem[33792];   // 4 A-slots (32KB) / gbuf
  float* gbuf = (float*)smem;
  int tid = threadIdx.x;
  int cb = blockIdx.x, rb = blockIdx.y;
  int lane = tid & 63, w = tid >> 6;
  int rsub = lane >> 3;
  int usw  = (((lane & 7) ^ rsub) & 7) * 8;  // swizzled source unit offset
  int lr = lane & 15;
  int key = lr & 7;
  int ub = lane >> 4;
  f32x4 acc[4][2] = {};

  const bf16_t* bbase = whht + (((size_t)cb * 17) << 13) + ((w * 4) << 9) + lane * 8;
  bf16x8 breg[4][2][2];

  auto stageA = [&](int slot, int kt){
    char* base = (char*)smem + slot * 8192;
    #pragma unroll
    for (int c = 0; c < 2; ++c){
      int q = w * 2 + c;
      int r = q * 8 + rsub;
      const bf16_t* g = hin + (size_t)(rb * 64 + r) * HLD + kt * 64 + usw;
      __builtin_amdgcn_global_load_lds((const void*)g, (void*)(base + q * 1024), 16, 0, 0);
    }
  };
  auto loadB = [&](int slot, int kt){
    #pragma unroll
    for (int ni = 0; ni < 2; ++ni)
      #pragma unroll
      for (int kk = 0; kk < 2; ++kk)
        breg[slot][ni][kk] = *reinterpret_cast<const bf16x8*>(
            bbase + ((size_t)kt << 13) + ((ni * 2 + kk) << 9));
  };
  auto compute = [&](int kt){
    const bf16_t* sA = (const bf16_t*)((const char*)smem + (kt & 3) * 8192);
    const int s = kt & 3;
    #pragma unroll
    for (int kk = 0; kk < 2; ++kk){
      int uo = ((kk * 4 + ub) ^ key) * 8;
      bf16x8 a[4];
      #pragma unroll
      for (int mi = 0; mi < 4; ++mi)
        a[mi] = *reinterpret_cast<const bf16x8*>(sA + (mi * 16 + lr) * 64 + uo);
      #pragma unroll
      for (int mi = 0; mi < 4; ++mi){
        acc[mi][0] = __builtin_amdgcn_mfma_f32_16x16x32_bf16(a[mi], breg[s][0][kk], acc[mi][0], 0, 0, 0);
        acc[mi][1] = __builtin_amdgcn_mfma_f32_16x16x32_bf16(a[mi], breg[s][1][kk], acc[mi][1], 0, 0, 0);
      }
    }
  };

  // prologue: interleaved B(i),A(i) — makes the wait count uniform
  loadB(0, 0); stageA(0, 0);
  loadB(1, 1); stageA(1, 1);
  loadB(2, 2); stageA(2, 2);

  #pragma unroll
  for (int kt = 0; kt < 14; ++kt){
    loadB((kt + 3) & 3, kt + 3);
    stageA((kt + 3) & 3, kt + 3);
    asm volatile("s_waitcnt vmcnt(18)" ::: "memory");   // exact: 3 iters x 6 ops younger
    __builtin_amdgcn_sched_barrier(0);
    __builtin_amdgcn_s_barrier();
    compute(kt);
    __builtin_amdgcn_s_barrier();
  }
  asm volatile("s_waitcnt vmcnt(12)" ::: "memory");
  __builtin_amdgcn_sched_barrier(0);
  __builtin_amdgcn_s_barrier();
  compute(14);
  __builtin_amdgcn_s_barrier();
  asm volatile("s_waitcnt vmcnt(6)" ::: "memory");
  __builtin_amdgcn_sched_barrier(0);
  __builtin_amdgcn_s_barrier();
  compute(15);
  __builtin_amdgcn_s_barrier();
  asm volatile("s_waitcnt vmcnt(0)" ::: "memory");
  __builtin_amdgcn_sched_barrier(0);
  __builtin_amdgcn_s_barrier();
  compute(16);
  __syncthreads();   // full drain before LDS reuse as gbuf

  // epilogue: xconst (+ begin at t==0), gate exchange via LDS, fused cell
  int lg = lane >> 4;
  #pragma unroll
  for (int mi = 0; mi < 4; ++mi)
    #pragma unroll
    for (int ni = 0; ni < 2; ++ni)
      #pragma unroll
      for (int r = 0; r < 4; ++r){
        int cl = ni * 16 + lr;
        int ng = w * 1024 + cb * 32 + cl;
        int rl = mi * 16 + lg * 4 + r;
        int rowg = rb * 64 + rl;
        float v = acc[mi][ni][r] + xconst[(size_t)rowg * 4096 + ng];
        if (t == 0) v += w_ih[(size_t)ng * DINn + 1040];
        gbuf[(w * 64 + rl) * 33 + cl] = v;
      }
  __syncthreads();
  #pragma unroll
  for (int rep = 0; rep < 8; ++rep){
    int cell = tid + rep * 256;
    int rl = cell >> 5, cl = cell & 31;
    float gi = gbuf[(0 * 64 + rl) * 33 + cl];
    float gf = gbuf[(1 * 64 + rl) * 33 + cl];
    float gg = gbuf[(2 * 64 + rl) * 33 + cl];
    float go = gbuf[(3 * 64 + rl) * 33 + cl];
    int rowg = rb * 64 + rl, colg = cb * 32 + cl;
    size_t o = (size_t)rowg * 1024 + colg;
    float mo = m[o];
    float mn = sigm(gf) * mo + sigm(gi) * tanhf(gg);
    m[o] = mn;
    float hn = sigm(go) * tanhf(mn);
    hout[(size_t)rowg * HLD + colg] = (bf16_t)hn;
  }
}

// ---------- batched out GEMM: async 3-buffer pipeline + XCD A-locality ----------
// 1D grid 3456: id = xcd + 8*(cb + 9*grp); rb = xcd + 8*grp.
// Per iter: stage(kt+2) [2 A + 4 B via swizzled-source global_load_lds] ->
// vmcnt(12) -> raw barrier -> MFMA (swizzled read) -> raw barrier. Tail 6/0.
// OOB B rows (ng>=1090) source-clamped; their acc entries are never stored.
__global__ __launch_bounds__(256) void k_out(
    const bf16_t* __restrict__ h,      // hs + HSTEP: 24576 rows, stride 1088
    const bf16_t* __restrict__ fcwb,
    const float* __restrict__ fc_b, const int* __restrict__ length,
    float* __restrict__ out){
  __shared__ __align__(16) unsigned char smem[73728];   // 3 x 24576
  int tid = threadIdx.x;
  int id  = blockIdx.x;
  int xcd = id & 7;
  int rem = id >> 3;
  int cb  = rem % 9;
  int grp = rem / 9;
  int rb  = xcd + 8 * grp;               // 0..383
  int lane = tid & 63, w = tid >> 6;
  int rsub = lane >> 3;
  int usw  = (((lane & 7) ^ rsub) & 7) * 8;
  int lr = lane & 15;
  int key = lr & 7;
  int ub = lane >> 4;
  f32x4 acc[4][2] = {};

  auto stage = [&](int buf, int kt){
    char* base = (char*)smem + buf * 24576;
    #pragma unroll
    for (int c = 0; c < 2; ++c){
      int q = w * 2 + c;
      int r = q * 8 + rsub;
      const bf16_t* g = h + (size_t)(rb * 64 + r) * HLD + kt * 64 + usw;
      __builtin_amdgcn_global_load_lds((const void*)g, (void*)(base + q * 1024), 16, 0, 0);
    }
    #pragma unroll
    for (int c = 0; c < 4; ++c){
      int q = w * 4 + c;
      int r = q * 8 + rsub;
      int n = cb * 128 + r;
      int ncl = (n < NOn) ? n : (NOn - 1);   // clamp: garbage only in unused acc
      const bf16_t* g = fcwb + (size_t)ncl * 1024 + kt * 64 + usw;
      __builtin_amdgcn_global_load_lds((const void*)g, (void*)(base + 8192 + q * 1024), 16, 0, 0);
    }
  };
  auto compute = [&](int buf){
    const bf16_t* sA = (const bf16_t*)((const char*)smem + buf * 24576);
    const bf16_t* sB = sA + 4096;
    #pragma unroll
    for (int kk = 0; kk < 2; ++kk){
      int uo = ((kk * 4 + ub) ^ key) * 8;
      bf16x8 a[4], bb[2];
      #pragma unroll
      for (int mi = 0; mi < 4; ++mi)
        a[mi] = *reinterpret_cast<const bf16x8*>(sA + (mi * 16 + lr) * 64 + uo);
      #pragma unroll
      for (int ni = 0; ni < 2; ++ni)
        bb[ni] = *reinterpret_cast<const bf16x8*>(sB + (w * 32 + ni * 16 + lr) * 64 + uo);
      #pragma unroll
      for (int mi = 0; mi < 4; ++mi)
        #pragma unroll
        for (int ni = 0; ni < 2; ++ni)
          acc[mi][ni] = __builtin_amdgcn_mfma_f32_16x16x32_bf16(a[mi], bb[ni], acc[mi][ni], 0, 0, 0);
    }
  };

  stage(0, 0);
  stage(1, 1);
  #pragma unroll
  for (int kt = 0; kt < 14; ++kt){
    stage((kt + 2) % 3, kt + 2);
    asm volatile("s_waitcnt vmcnt(12)" ::: "memory");
    __builtin_amdgcn_sched_barrier(0);
    __builtin_amdgcn_s_barrier();
    compute(kt % 3);
    __builtin_amdgcn_s_barrier();
  }
  asm volatile("s_waitcnt vmcnt(6)" ::: "memory");
  __builtin_amdgcn_sched_barrier(0);
  __builtin_amdgcn_s_barrier();
  compute(14 % 3);
  __builtin_amdgcn_s_barrier();
  asm volatile("s_waitcnt vmcnt(0)" ::: "memory");
  __builtin_amdgcn_sched_barrier(0);
  __builtin_amdgcn_s_barrier();
  compute(15 % 3);

  int lg = lane >> 4;
  #pragma unroll
  for (int mi = 0; mi < 4; ++mi)
    #pragma unroll
    for (int ni = 0; ni < 2; ++ni)
      #pragma unroll
      for (int r = 0; r < 4; ++r){
        int ng = cb * 128 + w * 32 + ni * 16 + lr;
        if (ng >= NOn) continue;
        int rg = rb * 64 + mi * 16 + lg * 4 + r;
        int tt = rg >> 9, b = rg & 511;
        float v = acc[mi][ni][r] + fc_b[ng];
        float mask = (tt < length[b]) ? 1.0f : 0.0f;
        if      (ng < 64)    out[(size_t)rg * 64 + ng] = sigm(v) * mask;
        else if (ng < 1088)  out[(size_t)1572864 + (size_t)rg * 1024 + (ng - 64)] = fmaxf(v, 0.f) * mask;
        else if (ng == 1088) out[(size_t)26738688 + rg] = sigm(v) * mask;
        else                 out[(size_t)26763264 + rg] = __expf(v) * mask;
      }
}

extern "C" void kernel_launch(void* const* d_in, const int* in_sizes, int n_in,
                              void* d_out, int out_size, void* d_ws, size_t ws_size,
                              hipStream_t stream){
  const float* image  = (const float*)d_in[0];
  const float* vp     = (const float*)d_in[1];
  const float* label  = (const float*)d_in[2];
  const int*   length = (const int*)  d_in[3];
  const float* fc_h_w = (const float*)d_in[4];
  const float* fc_h_b = (const float*)d_in[5];
  const float* fc_m_w = (const float*)d_in[6];
  const float* fc_m_b = (const float*)d_in[7];
  const float* w_ih   = (const float*)d_in[8];
  const float* w_hh   = (const float*)d_in[9];
  const float* b_ih   = (const float*)d_in[10];
  const float* b_hh   = (const float*)d_in[11];
  const float* fc_w   = (const float*)d_in[12];
  const float* fc_b   = (const float*)d_in[13];
  float* out = (float*)d_out;

  char* ws = (char*)d_ws;
  bf16_t* imb    = (bf16_t*)(ws + 0);           // 1 MB
  bf16_t* hs     = (bf16_t*)(ws + 1048576);     // 49 x 512 x 1088 bf16 = 54.6 MB
  float*  m      = (float*) (ws + 55640064);    // 2 MB
  float*  xconst = (float*) (ws + 57737216);    // 8 MB
  bf16_t* whht   = (bf16_t*)(ws + 66125824);    // packed 4096x1088 = 8.9 MB
  bf16_t* wimgb  = (bf16_t*)(ws + 75038720);    // 8 MB
  bf16_t* fchwb  = (bf16_t*)(ws + 83427328);    // 2 MB
  bf16_t* fcmwb  = (bf16_t*)(ws + 85524480);    // 2 MB
  bf16_t* fcwb   = (bf16_t*)(ws + 87621632);    // 2.2 MB (ends 89853952)

  k_mean   <<<dim3(512),  dim3(256), 0, stream>>>(image, imb);
  k_convert<<<dim3(2048), dim3(256), 0, stream>>>(w_hh, fc_h_w, fc_m_w, fc_w, label, w_ih,
                                                  whht, fchwb, fcmwb, fcwb, wimgb, hs);
  k_vpc    <<<dim3(8192), dim3(256), 0, stream>>>(w_ih, vp, b_ih, b_hh, xconst);
  k_init_gemm<<<dim3(48, 8), dim3(256), 0, stream>>>(imb, fchwb, fcmwb, wimgb,
                                                     fc_h_b, fc_m_b, hs, m, xconst);
  for (int t = 0; t < Tn; ++t){
    k_step<<<dim3(32, 8), dim3(256), 0, stream>>>(hs + (size_t)t * HSTEP,
                                                  hs + (size_t)(t + 1) * HSTEP,
                                                  whht, xconst, w_ih, m, t);
  }
  k_out<<<dim3(3456), dim3(256), 0, stream>>>(hs + (size_t)HSTEP, fcwb, fc_b, length, out);
}

// Round 17
// 910.589 us; speedup vs baseline: 1.0136x; 1.0136x over previous
//
#include <hip/hip_runtime.h>
#include <hip/hip_bf16.h>
#include <cstdint>

// ReportDecoder: B=512,S=49,E=1024,H=1024,V2=16,L=64,T=48, D_IN=1105
// Round 17: k_step "stage-all" restructure — all 17 A-tiles staged to LDS up
// front (139KB), ONE vmcnt(0)+barrier, then a barrier-free fully-unrolled K-loop
// (B reg-loads + swizzled LDS reads + MFMA, compiler-scheduled). Removes the
// 34-barrier/17-wait per-iteration rhythm that 4 pipeline variants couldn't beat.
// k_out (async 3-buffer, conflict-free) and preamble identical to r16.

typedef __bf16 bf16_t;
typedef bf16_t bf16x8 __attribute__((ext_vector_type(8)));
typedef bf16_t bf16x4 __attribute__((ext_vector_type(4)));
typedef float  f32x4  __attribute__((ext_vector_type(4)));

#define Bn    512
#define Sn    49
#define En    1024
#define Hn    1024
#define Ln    64
#define Tn    48
#define DINn  1105
#define NOn   1090
#define HLD   1088          // h row stride (1024 h + 64 label)
#define HSTEP 557056        // 512*1088 elements per step slab

#define BM   64
#define LDSP 72             // padded K-stride for init GEMM LDS tiles

__device__ __forceinline__ float sigm(float x){ return 1.0f / (1.0f + __expf(-x)); }

// ---------- image mean ----------
__global__ __launch_bounds__(256) void k_mean(const float* __restrict__ image,
                                              bf16_t* __restrict__ imb){
  int b  = blockIdx.x;
  int e0 = threadIdx.x * 4;
  const float* p = image + (size_t)b * (Sn * En) + e0;
  float4 acc = make_float4(0.f, 0.f, 0.f, 0.f);
  for (int s = 0; s < Sn; ++s){
    float4 v = *reinterpret_cast<const float4*>(p + (size_t)s * En);
    acc.x += v.x; acc.y += v.y; acc.z += v.z; acc.w += v.w;
  }
  const float inv = 1.0f / 49.0f;
  bf16x4 o;
  o[0] = (bf16_t)(acc.x * inv); o[1] = (bf16_t)(acc.y * inv);
  o[2] = (bf16_t)(acc.z * inv); o[3] = (bf16_t)(acc.w * inv);
  *reinterpret_cast<bf16x4*>(imb + (size_t)b * En + e0) = o;
}

// ---------- conversions: whht packed tiles, fc weights, wimg, label scatter ----------
__global__ __launch_bounds__(256) void k_convert(
    const float* __restrict__ w_hh,  const float* __restrict__ fc_h_w,
    const float* __restrict__ fc_m_w,const float* __restrict__ fc_w,
    const float* __restrict__ label, const float* __restrict__ w_ih,
    bf16_t* __restrict__ whht,  bf16_t* __restrict__ fchwb,
    bf16_t* __restrict__ fcmwb, bf16_t* __restrict__ fcwb,
    bf16_t* __restrict__ wimgb, bf16_t* __restrict__ hs){
  const int E0 = 32 * 17 * 16 * 512;     // whht packed (= 4096*1088)
  const int E1 = E0 + 1024 * 1024;
  const int E2 = E1 + 1024 * 1024;
  const int E3 = E2 + 1090 * 1024;
  const int E4 = E3 + 4096 * 1024;
  const int E5 = E4 + 48 * 512 * 64;
  int stride = gridDim.x * blockDim.x;
  for (int i = blockIdx.x * blockDim.x + threadIdx.x; i < E5; i += stride){
    if (i < E0){
      int e = i & 7, l = (i >> 3) & 63, g = (i >> 9) & 15;
      int rest = i >> 13;                // cb*17 + kt
      int kt = rest % 17, cbb = rest / 17;
      int wv = g >> 2, ni = (g >> 1) & 1, kk = g & 1;
      int n = wv * 1024 + cbb * 32 + ni * 16 + (l & 15);
      int k = kt * 64 + kk * 32 + (l >> 4) * 8 + e;
      float v = (k < 1024) ? w_hh[(size_t)n * 1024 + k]
                           : w_ih[(size_t)n * DINn + 1041 + (k - 1024)];
      whht[i] = (bf16_t)v;
    } else if (i < E1){ int j = i - E0; fchwb[j] = (bf16_t)fc_h_w[j]; }
    else if (i < E2){ int j = i - E1; fcmwb[j] = (bf16_t)fc_m_w[j]; }
    else if (i < E3){ int j = i - E2; fcwb[j]  = (bf16_t)fc_w[j]; }
    else if (i < E4){
      int j = i - E3; int n = j >> 10, k = j & 1023;
      wimgb[j] = (bf16_t)w_ih[(size_t)n * DINn + k];
    } else {
      int j = i - E4;
      int t = j >> 15, rem = j & 32767, row = rem >> 6, c = rem & 63;
      float v = (t == 0) ? 0.f : label[(size_t)row * (Sn * Ln) + (t - 1) * 64 + c];
      hs[((size_t)t * 512 + row) * HLD + 1024 + c] = (bf16_t)v;
    }
  }
}

// ---------- xconst pre-pass ----------
__global__ __launch_bounds__(256) void k_vpc(const float* __restrict__ w_ih,
                                             const float* __restrict__ vp,
                                             const float* __restrict__ b_ih,
                                             const float* __restrict__ b_hh,
                                             float* __restrict__ xconst){
  int idx = blockIdx.x * 256 + threadIdx.x;
  int b = idx >> 12, n = idx & 4095;
  float acc = b_ih[n] + b_hh[n];
  const float* w = w_ih + (size_t)n * DINn + En;
  const float* v = vp + b * 16;
  #pragma unroll
  for (int j = 0; j < 16; ++j) acc += v[j] * w[j];
  xconst[idx] = acc;
}

// ---------- padded-LDS helpers (init GEMM) ----------
__device__ __forceinline__ void stageAp(bf16_t* sA, const bf16_t* gptr, int ld, int tid){
  #pragma unroll
  for (int i = 0; i < 2; ++i){
    int idx = tid + i * 256;
    int r = idx >> 3, v = idx & 7;
    *reinterpret_cast<bf16x8*>(sA + r * LDSP + v * 8) =
      *reinterpret_cast<const bf16x8*>(gptr + (size_t)r * ld + v * 8);
  }
}

__device__ __forceinline__ void mma_tile(const bf16_t* sA, const bf16_t* sB,
                                         f32x4 (&acc)[4][2], int lane, int w){
  int lr = lane & 15;
  int lk = (lane >> 4) * 8;
  #pragma unroll
  for (int kk = 0; kk < 2; ++kk){
    bf16x8 a[4], bb[2];
    #pragma unroll
    for (int mi = 0; mi < 4; ++mi)
      a[mi] = *reinterpret_cast<const bf16x8*>(sA + (mi * 16 + lr) * LDSP + kk * 32 + lk);
    #pragma unroll
    for (int ni = 0; ni < 2; ++ni)
      bb[ni] = *reinterpret_cast<const bf16x8*>(sB + (w * 32 + ni * 16 + lr) * LDSP + kk * 32 + lk);
    #pragma unroll
    for (int mi = 0; mi < 4; ++mi)
      #pragma unroll
      for (int ni = 0; ni < 2; ++ni)
        acc[mi][ni] = __builtin_amdgcn_mfma_f32_16x16x32_bf16(a[mi], bb[ni], acc[mi][ni], 0, 0, 0);
  }
}

// ---------- init GEMM: h0 (stride 1088), m0, xconst += im@Wimg^T ----------
__global__ __launch_bounds__(256) void k_init_gemm(
    const bf16_t* __restrict__ imb,  const bf16_t* __restrict__ fchw,
    const bf16_t* __restrict__ fcmw, const bf16_t* __restrict__ wimg,
    const float* __restrict__ fc_h_b,const float* __restrict__ fc_m_b,
    bf16_t* __restrict__ h0, float* __restrict__ m0, float* __restrict__ xconst){
  __shared__ __align__(16) unsigned char smem[(BM + 128) * LDSP * 2];
  bf16_t* sA = (bf16_t*)smem;
  bf16_t* sB = (bf16_t*)(smem + BM * LDSP * 2);
  int tid = threadIdx.x;
  int cb = blockIdx.x, rb = blockIdx.y;
  int nBase = cb * 128;
  const bf16_t* Bsrc; int nOff;
  if      (nBase < 1024){ Bsrc = fchw; nOff = nBase; }
  else if (nBase < 2048){ Bsrc = fcmw; nOff = nBase - 1024; }
  else                  { Bsrc = wimg; nOff = nBase - 2048; }

  f32x4 acc[4][2] = {};
  int lane = tid & 63, w = tid >> 6;
  for (int kt = 0; kt < 16; ++kt){
    stageAp(sA, imb + (size_t)(rb * 64) * 1024 + kt * 64, 1024, tid);
    #pragma unroll
    for (int i = 0; i < 4; ++i){
      int idx = tid + i * 256;
      int r = idx >> 3, v = idx & 7;
      *reinterpret_cast<bf16x8*>(sB + r * LDSP + v * 8) =
        *reinterpret_cast<const bf16x8*>(Bsrc + (size_t)(nOff + r) * 1024 + kt * 64 + v * 8);
    }
    __syncthreads();
    mma_tile(sA, sB, acc, lane, w);
    __syncthreads();
  }
  int lr = lane & 15, lg = lane >> 4;
  #pragma unroll
  for (int mi = 0; mi < 4; ++mi)
    #pragma unroll
    for (int ni = 0; ni < 2; ++ni)
      #pragma unroll
      for (int r = 0; r < 4; ++r){
        int ng   = nBase + w * 32 + ni * 16 + lr;
        int rowg = rb * 64 + mi * 16 + lg * 4 + r;
        float v = acc[mi][ni][r];
        if (ng < 1024){
          h0[(size_t)rowg * HLD + ng] = (bf16_t)tanhf(v + fc_h_b[ng]);
        } else if (ng < 2048){
          int n = ng - 1024;
          m0[(size_t)rowg * 1024 + n] = tanhf(v + fc_m_b[n]);
        } else {
          int n = ng - 2048;
          xconst[(size_t)rowg * 4096 + n] += v;
        }
      }
}

// ---------- per-step fused gates GEMM + LSTM cell (stage-all, barrier-free loop) ----
// grid (32,8). All 17 A-tiles staged up front (139KB LDS, swizzled source);
// single vmcnt(0)+barrier; then fully-unrolled compiler-scheduled K-loop
// (B reg-loads + swizzled LDS reads + 16 MFMA per kt, no barriers/waits).
__global__ __launch_bounds__(256) void k_step(
    const bf16_t* __restrict__ hin,
    bf16_t* __restrict__ hout,
    const bf16_t* __restrict__ whht,   // packed [cb][17][16][512]
    const float* __restrict__ xconst,  // 512 x 4096
    const float* __restrict__ w_ih,    // begin col 1040
    float* __restrict__ m,             // 512 x 1024 f32
    int t){
  __shared__ __align__(16) unsigned char smem[139264];  // 17 x 8192 A tiles
  float* gbuf = (float*)smem;                           // reused post-loop
  int tid = threadIdx.x;
  int cb = blockIdx.x, rb = blockIdx.y;
  int lane = tid & 63, w = tid >> 6;
  int rsub = lane >> 3;
  int usw  = (((lane & 7) ^ rsub) & 7) * 8;  // swizzled source unit offset
  int lr = lane & 15;
  int key = lr & 7;
  int ub = lane >> 4;
  f32x4 acc[4][2] = {};

  const bf16_t* bbase = whht + (((size_t)cb * 17) << 13) + ((w * 4) << 9) + lane * 8;

  // stage ALL 17 kt tiles (34 global_load_lds per thread; vmcnt max 63 ok)
  #pragma unroll
  for (int kt = 0; kt < 17; ++kt){
    char* base = (char*)smem + kt * 8192;
    #pragma unroll
    for (int c = 0; c < 2; ++c){
      int q = w * 2 + c;
      int r = q * 8 + rsub;
      const bf16_t* g = hin + (size_t)(rb * 64 + r) * HLD + kt * 64 + usw;
      __builtin_amdgcn_global_load_lds((const void*)g, (void*)(base + q * 1024), 16, 0, 0);
    }
  }
  asm volatile("s_waitcnt vmcnt(0)" ::: "memory");
  __builtin_amdgcn_sched_barrier(0);
  __builtin_amdgcn_s_barrier();

  // barrier-free K loop — compiler schedules B loads / LDS reads / MFMA freely
  #pragma unroll
  for (int kt = 0; kt < 17; ++kt){
    bf16x8 b00 = *reinterpret_cast<const bf16x8*>(bbase + ((size_t)kt << 13) + (0 << 9));
    bf16x8 b01 = *reinterpret_cast<const bf16x8*>(bbase + ((size_t)kt << 13) + (1 << 9));
    bf16x8 b10 = *reinterpret_cast<const bf16x8*>(bbase + ((size_t)kt << 13) + (2 << 9));
    bf16x8 b11 = *reinterpret_cast<const bf16x8*>(bbase + ((size_t)kt << 13) + (3 << 9));
    const bf16_t* sA = (const bf16_t*)((const char*)smem + kt * 8192);
    #pragma unroll
    for (int kk = 0; kk < 2; ++kk){
      int uo = ((kk * 4 + ub) ^ key) * 8;
      bf16x8 a[4];
      #pragma unroll
      for (int mi = 0; mi < 4; ++mi)
        a[mi] = *reinterpret_cast<const bf16x8*>(sA + (mi * 16 + lr) * 64 + uo);
      bf16x8 bk0 = (kk == 0) ? b00 : b01;
      bf16x8 bk1 = (kk == 0) ? b10 : b11;
      #pragma unroll
      for (int mi = 0; mi < 4; ++mi){
        acc[mi][0] = __builtin_amdgcn_mfma_f32_16x16x32_bf16(a[mi], bk0, acc[mi][0], 0, 0, 0);
        acc[mi][1] = __builtin_amdgcn_mfma_f32_16x16x32_bf16(a[mi], bk1, acc[mi][1], 0, 0, 0);
      }
    }
  }
  __syncthreads();   // all LDS reads done before reuse as gbuf

  // epilogue: xconst (+ begin at t==0), gate exchange via LDS, fused cell
  int lg = lane >> 4;
  #pragma unroll
  for (int mi = 0; mi < 4; ++mi)
    #pragma unroll
    for (int ni = 0; ni < 2; ++ni)
      #pragma unroll
      for (int r = 0; r < 4; ++r){
        int cl = ni * 16 + lr;
        int ng = w * 1024 + cb * 32 + cl;
        int rl = mi * 16 + lg * 4 + r;
        int rowg = rb * 64 + rl;
        float v = acc[mi][ni][r] + xconst[(size_t)rowg * 4096 + ng];
        if (t == 0) v += w_ih[(size_t)ng * DINn + 1040];
        gbuf[(w * 64 + rl) * 33 + cl] = v;
      }
  __syncthreads();
  #pragma unroll
  for (int rep = 0; rep < 8; ++rep){
    int cell = tid + rep * 256;
    int rl = cell >> 5, cl = cell & 31;
    float gi = gbuf[(0 * 64 + rl) * 33 + cl];
    float gf = gbuf[(1 * 64 + rl) * 33 + cl];
    float gg = gbuf[(2 * 64 + rl) * 33 + cl];
    float go = gbuf[(3 * 64 + rl) * 33 + cl];
    int rowg = rb * 64 + rl, colg = cb * 32 + cl;
    size_t o = (size_t)rowg * 1024 + colg;
    float mo = m[o];
    float mn = sigm(gf) * mo + sigm(gi) * tanhf(gg);
    m[o] = mn;
    float hn = sigm(go) * tanhf(mn);
    hout[(size_t)rowg * HLD + colg] = (bf16_t)hn;
  }
}

// ---------- batched out GEMM: async 3-buffer pipeline + XCD A-locality ----------
__global__ __launch_bounds__(256) void k_out(
    const bf16_t* __restrict__ h,      // hs + HSTEP: 24576 rows, stride 1088
    const bf16_t* __restrict__ fcwb,
    const float* __restrict__ fc_b, const int* __restrict__ length,
    float* __restrict__ out){
  __shared__ __align__(16) unsigned char smem[73728];   // 3 x 24576
  int tid = threadIdx.x;
  int id  = blockIdx.x;
  int xcd = id & 7;
  int rem = id >> 3;
  int cb  = rem % 9;
  int grp = rem / 9;
  int rb  = xcd + 8 * grp;               // 0..383
  int lane = tid & 63, w = tid >> 6;
  int rsub = lane >> 3;
  int usw  = (((lane & 7) ^ rsub) & 7) * 8;
  int lr = lane & 15;
  int key = lr & 7;
  int ub = lane >> 4;
  f32x4 acc[4][2] = {};

  auto stage = [&](int buf, int kt){
    char* base = (char*)smem + buf * 24576;
    #pragma unroll
    for (int c = 0; c < 2; ++c){
      int q = w * 2 + c;
      int r = q * 8 + rsub;
      const bf16_t* g = h + (size_t)(rb * 64 + r) * HLD + kt * 64 + usw;
      __builtin_amdgcn_global_load_lds((const void*)g, (void*)(base + q * 1024), 16, 0, 0);
    }
    #pragma unroll
    for (int c = 0; c < 4; ++c){
      int q = w * 4 + c;
      int r = q * 8 + rsub;
      int n = cb * 128 + r;
      int ncl = (n < NOn) ? n : (NOn - 1);   // clamp: garbage only in unused acc
      const bf16_t* g = fcwb + (size_t)ncl * 1024 + kt * 64 + usw;
      __builtin_amdgcn_global_load_lds((const void*)g, (void*)(base + 8192 + q * 1024), 16, 0, 0);
    }
  };
  auto compute = [&](int buf){
    const bf16_t* sA = (const bf16_t*)((const char*)smem + buf * 24576);
    const bf16_t* sB = sA + 4096;
    #pragma unroll
    for (int kk = 0; kk < 2; ++kk){
      int uo = ((kk * 4 + ub) ^ key) * 8;
      bf16x8 a[4], bb[2];
      #pragma unroll
      for (int mi = 0; mi < 4; ++mi)
        a[mi] = *reinterpret_cast<const bf16x8*>(sA + (mi * 16 + lr) * 64 + uo);
      #pragma unroll
      for (int ni = 0; ni < 2; ++ni)
        bb[ni] = *reinterpret_cast<const bf16x8*>(sB + (w * 32 + ni * 16 + lr) * 64 + uo);
      #pragma unroll
      for (int mi = 0; mi < 4; ++mi)
        #pragma unroll
        for (int ni = 0; ni < 2; ++ni)
          acc[mi][ni] = __builtin_amdgcn_mfma_f32_16x16x32_bf16(a[mi], bb[ni], acc[mi][ni], 0, 0, 0);
    }
  };

  stage(0, 0);
  stage(1, 1);
  #pragma unroll
  for (int kt = 0; kt < 14; ++kt){
    stage((kt + 2) % 3, kt + 2);
    asm volatile("s_waitcnt vmcnt(12)" ::: "memory");
    __builtin_amdgcn_sched_barrier(0);
    __builtin_amdgcn_s_barrier();
    compute(kt % 3);
    __builtin_amdgcn_s_barrier();
  }
  asm volatile("s_waitcnt vmcnt(6)" ::: "memory");
  __builtin_amdgcn_sched_barrier(0);
  __builtin_amdgcn_s_barrier();
  compute(14 % 3);
  __builtin_amdgcn_s_barrier();
  asm volatile("s_waitcnt vmcnt(0)" ::: "memory");
  __builtin_amdgcn_sched_barrier(0);
  __builtin_amdgcn_s_barrier();
  compute(15 % 3);

  int lg = lane >> 4;
  #pragma unroll
  for (int mi = 0; mi < 4; ++mi)
    #pragma unroll
    for (int ni = 0; ni < 2; ++ni)
      #pragma unroll
      for (int r = 0; r < 4; ++r){
        int ng = cb * 128 + w * 32 + ni * 16 + lr;
        if (ng >= NOn) continue;
        int rg = rb * 64 + mi * 16 + lg * 4 + r;
        int tt = rg >> 9, b = rg & 511;
        float v = acc[mi][ni][r] + fc_b[ng];
        float mask = (tt < length[b]) ? 1.0f : 0.0f;
        if      (ng < 64)    out[(size_t)rg * 64 + ng] = sigm(v) * mask;
        else if (ng < 1088)  out[(size_t)1572864 + (size_t)rg * 1024 + (ng - 64)] = fmaxf(v, 0.f) * mask;
        else if (ng == 1088) out[(size_t)26738688 + rg] = sigm(v) * mask;
        else                 out[(size_t)26763264 + rg] = __expf(v) * mask;
      }
}

extern "C" void kernel_launch(void* const* d_in, const int* in_sizes, int n_in,
                              void* d_out, int out_size, void* d_ws, size_t ws_size,
                              hipStream_t stream){
  const float* image  = (const float*)d_in[0];
  const float* vp     = (const float*)d_in[1];
  const float* label  = (const float*)d_in[2];
  const int*   length = (const int*)  d_in[3];
  const float* fc_h_w = (const float*)d_in[4];
  const float* fc_h_b = (const float*)d_in[5];
  const float* fc_m_w = (const float*)d_in[6];
  const float* fc_m_b = (const float*)d_in[7];
  const float* w_ih   = (const float*)d_in[8];
  const float* w_hh   = (const float*)d_in[9];
  const float* b_ih   = (const float*)d_in[10];
  const float* b_hh   = (const float*)d_in[11];
  const float* fc_w   = (const float*)d_in[12];
  const float* fc_b   = (const float*)d_in[13];
  float* out = (float*)d_out;

  char* ws = (char*)d_ws;
  bf16_t* imb    = (bf16_t*)(ws + 0);           // 1 MB
  bf16_t* hs     = (bf16_t*)(ws + 1048576);     // 49 x 512 x 1088 bf16 = 54.6 MB
  float*  m      = (float*) (ws + 55640064);    // 2 MB
  float*  xconst = (float*) (ws + 57737216);    // 8 MB
  bf16_t* whht   = (bf16_t*)(ws + 66125824);    // packed 4096x1088 = 8.9 MB
  bf16_t* wimgb  = (bf16_t*)(ws + 75038720);    // 8 MB
  bf16_t* fchwb  = (bf16_t*)(ws + 83427328);    // 2 MB
  bf16_t* fcmwb  = (bf16_t*)(ws + 85524480);    // 2 MB
  bf16_t* fcwb   = (bf16_t*)(ws + 87621632);    // 2.2 MB (ends 89853952)

  k_mean   <<<dim3(512),  dim3(256), 0, stream>>>(image, imb);
  k_convert<<<dim3(2048), dim3(256), 0, stream>>>(w_hh, fc_h_w, fc_m_w, fc_w, label, w_ih,
                                                  whht, fchwb, fcmwb, fcwb, wimgb, hs);
  k_vpc    <<<dim3(8192), dim3(256), 0, stream>>>(w_ih, vp, b_ih, b_hh, xconst);
  k_init_gemm<<<dim3(48, 8), dim3(256), 0, stream>>>(imb, fchwb, fcmwb, wimgb,
                                                     fc_h_b, fc_m_b, hs, m, xconst);
  for (int t = 0; t < Tn; ++t){
    k_step<<<dim3(32, 8), dim3(256), 0, stream>>>(hs + (size_t)t * HSTEP,
                                                  hs + (size_t)(t + 1) * HSTEP,
                                                  whht, xconst, w_ih, m, t);
  }
  k_out<<<dim3(3456), dim3(256), 0, stream>>>(hs + (size_t)HSTEP, fcwb, fc_b, length, out);
}